// Round 6
// baseline (226.346 us; speedup 1.0000x reference)
//
#include <hip/hip_runtime.h>
#include <hip/hip_bf16.h>
#include <math.h>

// Problem constants
#define NN 50000
#define EE 800000
#define NB_SCAN 49  // ceil(50000/1024)

typedef __attribute__((ext_vector_type(8))) short bf16x8;
typedef __attribute__((ext_vector_type(4))) float f32x4;
typedef __attribute__((ext_vector_type(2))) float f32x2;
typedef __attribute__((ext_vector_type(8))) unsigned short ushortx8;

// ---------------- workspace layout (bytes), all 256B-aligned ----------------
#define OFF_XBF  ((size_t)0)                        // N*128 bf16 (x converted)
#define SZ_XBF   ((size_t)NN * 128 * 2)
#define OFF_XL1B (OFF_XBF + SZ_XBF)                 // N*128 bf16 (xl layer1)
#define SZ_XL1B  ((size_t)NN * 128 * 2)
#define OFF_XR1  (OFF_XL1B + SZ_XL1B)               // N*128 f32 (xr layer1)
#define SZ_XR1   ((size_t)NN * 128 * 4)
#define OFF_H1B  (OFF_XR1 + SZ_XR1)                 // N*128 bf16
#define SZ_H1B   ((size_t)NN * 128 * 2)
#define OFF_XL2B (OFF_H1B + SZ_H1B)                 // N*40 bf16
#define SZ_XL2B  ((size_t)NN * 40 * 2)
#define OFF_XR2  (OFF_XL2B + SZ_XL2B)               // N*40 f32
#define SZ_XR2   ((size_t)NN * 40 * 4)
#define OFF_BP1  (OFF_XR2 + SZ_XR2)                 // 4*16*64*8 bf16
#define SZ_BP1   ((size_t)32768 * 2)
#define OFF_BP2  (OFF_BP1 + SZ_BP1)                 // 4*5*64*8 bf16
#define SZ_BP2   ((size_t)10240 * 2)
#define OFF_BB1  (OFF_BP2 + SZ_BP2)                 // 256 f32
#define SZ_BB1   ((size_t)1024)
#define OFF_BB2  (OFF_BB1 + SZ_BB1)                 // 80 f32 (pad)
#define SZ_BB2   ((size_t)512)
#define OFF_DEG  (OFF_BB2 + SZ_BB2)                 // N int
#define SZ_DEG   ((size_t)NN * 4)
#define OFF_OFFS (OFF_DEG + SZ_DEG)                 // (N+1) int (pad)
#define SZ_OFFS  ((size_t)200192)
#define OFF_CUR  (OFF_OFFS + SZ_OFFS)               // N int
#define SZ_CUR   ((size_t)NN * 4)
#define OFF_CSR  (OFF_CUR + SZ_CUR)                 // E int
#define SZ_CSR   ((size_t)EE * 4)
#define OFF_BSUM (OFF_CSR + SZ_CSR)                 // 64 int
#define SZ_BSUM  ((size_t)256)

__device__ __forceinline__ unsigned short f2bf(float f) {
    union { float f; unsigned u; } v;
    v.f = f;
    unsigned r = v.u + 0x7fffu + ((v.u >> 16) & 1u);
    return (unsigned short)(r >> 16);
}
__device__ __forceinline__ f32x2 bf2f2(unsigned u) {
    union { unsigned u; float f; } lo, hi;
    lo.u = u << 16;
    hi.u = u & 0xffff0000u;
    f32x2 r;
    r.x = lo.f;
    r.y = hi.f;
    return r;
}

// packed f32 VOP3P helpers (compiler never auto-packs; 2 FLOP/inst)
__device__ __forceinline__ f32x2 pk_add(f32x2 a, f32x2 b) {
    f32x2 d;
    asm("v_pk_add_f32 %0, %1, %2" : "=v"(d) : "v"(a), "v"(b));
    return d;
}
__device__ __forceinline__ f32x2 pk_mul(f32x2 a, f32x2 b) {
    f32x2 d;
    asm("v_pk_mul_f32 %0, %1, %2" : "=v"(d) : "v"(a), "v"(b));
    return d;
}
__device__ __forceinline__ f32x2 pk_fma(f32x2 a, f32x2 b, f32x2 c) {
    f32x2 d;
    asm("v_pk_fma_f32 %0, %1, %2, %3" : "=v"(d) : "v"(a), "v"(b), "v"(c));
    return d;
}
__device__ __forceinline__ f32x2 pk_abs2(f32x2 a) {
    f32x2 r;
    r.x = __builtin_fabsf(a.x);
    r.y = __builtin_fabsf(a.y);
    return r;
}

// ---------------- fused prep: zero DEG + pack weights + cvt x -> bf16 --------
__global__ void prep_kernel(
    const float* __restrict__ x, unsigned short* __restrict__ XBF,
    const float* __restrict__ Wl1, const float* __restrict__ bl1,
    const float* __restrict__ Wr1, const float* __restrict__ br1,
    const float* __restrict__ Wl2, const float* __restrict__ bl2,
    const float* __restrict__ Wr2, const float* __restrict__ br2,
    unsigned short* __restrict__ BP1, float* __restrict__ BB1,
    unsigned short* __restrict__ BP2, float* __restrict__ BB2,
    int* __restrict__ DEG) {
    int i = blockIdx.x * blockDim.x + threadIdx.x;
    if (i < NN * 128 / 8) {
        const float4* p = (const float4*)x + (size_t)i * 2;
        float4 v0 = p[0], v1 = p[1];
        ushortx8 o;
        o[0] = f2bf(v0.x); o[1] = f2bf(v0.y); o[2] = f2bf(v0.z); o[3] = f2bf(v0.w);
        o[4] = f2bf(v1.x); o[5] = f2bf(v1.y); o[6] = f2bf(v1.z); o[7] = f2bf(v1.w);
        *((ushortx8*)XBF + i) = o;
    }
    if (i < NN) DEG[i] = 0;
    if (i < 32768) {  // layer 1 B-pack: NT=16
        int j = i & 7, l = (i >> 3) & 63, nt = (i >> 9) & 15, kt = i >> 13;
        int k = kt * 32 + ((l >> 4) << 3) + j;
        int n = nt * 16 + (l & 15);
        float v = (n < 128) ? Wl1[k * 128 + n] : Wr1[k * 128 + (n - 128)];
        BP1[i] = f2bf(v);
    }
    if (i < 10240) {  // layer 2 B-pack: NT=5
        int j = i & 7, l = (i >> 3) & 63;
        int rest = i >> 9;
        int nt = rest % 5, kt = rest / 5;
        int k = kt * 32 + ((l >> 4) << 3) + j;
        int n = nt * 16 + (l & 15);
        float v = (n < 40) ? Wl2[k * 40 + n] : Wr2[k * 40 + (n - 40)];
        BP2[i] = f2bf(v);
    }
    if (i < 256) BB1[i] = (i < 128) ? bl1[i] : br1[i - 128];
    if (i < 80) BB2[i] = (i < 40) ? bl2[i] : br2[i - 40];
}

__global__ void hist_kernel(const int* __restrict__ tgts, int* __restrict__ deg, int e_) {
    int e = blockIdx.x * blockDim.x + threadIdx.x;
    if (e < e_) atomicAdd(&deg[tgts[e]], 1);
}

// ---------------- parallel 3-phase scan ----------------
__global__ __launch_bounds__(1024) void scan_bsum_kernel(
    const int* __restrict__ deg, int* __restrict__ bsum, int n) {
    __shared__ int ws[16];
    int lane = threadIdx.x & 63, w = threadIdx.x >> 6;
    int i = blockIdx.x * 1024 + threadIdx.x;
    int v = (i < n) ? deg[i] : 0;
#pragma unroll
    for (int d = 32; d >= 1; d >>= 1) v += __shfl_xor(v, d, 64);
    if (lane == 0) ws[w] = v;
    __syncthreads();
    if (threadIdx.x < 16) {
        int xv = ws[threadIdx.x];
#pragma unroll
        for (int d = 8; d >= 1; d >>= 1) xv += __shfl_xor(xv, d, 16);
        if (threadIdx.x == 0) bsum[blockIdx.x] = xv;
    }
}

__global__ void scan_boff_kernel(int* __restrict__ bsum, int nb) {
    int tid = threadIdx.x;  // 64 threads, one wave
    int v = (tid < nb) ? bsum[tid] : 0;
    int incl = v;
#pragma unroll
    for (int d = 1; d < 64; d <<= 1) {
        int t = __shfl_up(incl, d, 64);
        if (tid >= d) incl += t;
    }
    if (tid < nb) bsum[tid] = incl - v;  // exclusive block offsets
}

__global__ __launch_bounds__(1024) void scan_final_kernel(
    const int* __restrict__ deg, const int* __restrict__ bsum,
    int* __restrict__ off, int* __restrict__ cur, int n) {
    __shared__ int wsum[16];
    int lane = threadIdx.x & 63, w = threadIdx.x >> 6;
    int carry = bsum[blockIdx.x];
    int i = blockIdx.x * 1024 + threadIdx.x;
    int v = (i < n) ? deg[i] : 0;
    int incl = v;
#pragma unroll
    for (int d = 1; d < 64; d <<= 1) {
        int t = __shfl_up(incl, d, 64);
        if (lane >= d) incl += t;
    }
    if (lane == 63) wsum[w] = incl;
    __syncthreads();
    if (threadIdx.x < 16) {
        int xv = wsum[threadIdx.x];
#pragma unroll
        for (int d = 1; d < 16; d <<= 1) {
            int t = __shfl_up(xv, d, 16);
            if ((int)threadIdx.x >= d) xv += t;
        }
        wsum[threadIdx.x] = xv;
    }
    __syncthreads();
    int add = (w > 0) ? wsum[w - 1] : 0;
    if (i < n) {
        int tot = carry + incl + add;
        off[i + 1] = tot;
        cur[i] = tot - v;
    }
    if (i == 0) off[0] = 0;
}

__global__ void scatter_kernel(const int* __restrict__ srcs, const int* __restrict__ tgts,
                               int* __restrict__ cur, int* __restrict__ csr, int e_) {
    int e = blockIdx.x * blockDim.x + threadIdx.x;
    if (e < e_) {
        int t = tgts[e];
        int pos = atomicAdd(&cur[t], 1);
        csr[pos] = srcs[e];
    }
}

// ---------------- bf16 MFMA GEMM with split bf16/f32 output ------------------
__global__ __launch_bounds__(256) void gemm_mfma_kernel(
    const unsigned short* __restrict__ Abf, const unsigned short* __restrict__ BP,
    const float* __restrict__ bias, unsigned short* __restrict__ Cbf,
    float* __restrict__ Cf, int M, int NT, int NSPLIT) {
    int wave = (blockIdx.x * blockDim.x + threadIdx.x) >> 6;
    int lane = threadIdx.x & 63;
    int r0 = wave * 16;
    if (r0 >= M) return;
    int koff = (lane >> 4) << 3;
    const unsigned short* ap = &Abf[(size_t)(r0 + (lane & 15)) * 128 + koff];
    bf16x8 a0 = *(const bf16x8*)(ap);
    bf16x8 a1 = *(const bf16x8*)(ap + 32);
    bf16x8 a2 = *(const bf16x8*)(ap + 64);
    bf16x8 a3 = *(const bf16x8*)(ap + 96);
    int NR = (NT << 4) - NSPLIT;
    int col = lane & 15;
    int rb = r0 + ((lane >> 4) << 2);
    size_t ktStride = (size_t)NT * 512;
    for (int nt = 0; nt < NT; ++nt) {
        const unsigned short* bp = &BP[((size_t)nt * 64 + lane) * 8];
        f32x4 acc = {0.f, 0.f, 0.f, 0.f};
        acc = __builtin_amdgcn_mfma_f32_16x16x32_bf16(a0, *(const bf16x8*)(bp), acc, 0, 0, 0);
        acc = __builtin_amdgcn_mfma_f32_16x16x32_bf16(a1, *(const bf16x8*)(bp + ktStride), acc, 0, 0, 0);
        acc = __builtin_amdgcn_mfma_f32_16x16x32_bf16(a2, *(const bf16x8*)(bp + 2 * ktStride), acc, 0, 0, 0);
        acc = __builtin_amdgcn_mfma_f32_16x16x32_bf16(a3, *(const bf16x8*)(bp + 3 * ktStride), acc, 0, 0, 0);
        int c = (nt << 4) + col;
        float bb = bias[c];
        if (c < NSPLIT) {
#pragma unroll
            for (int j = 0; j < 4; ++j) Cbf[(size_t)(rb + j) * NSPLIT + c] = f2bf(acc[j] + bb);
        } else {
#pragma unroll
            for (int j = 0; j < 4; ++j) Cf[(size_t)(rb + j) * NR + (c - NSPLIT)] = acc[j] + bb;
        }
    }
}

// ---------------- layer-1 fused edge kernel (4 edges x 16 lanes per wave) ----
// No max tracking (scores ~N(0,1); exp range safe in f32). Packed-f32 math.
// lrelu(h) = 0.6h + 0.4|h|.
__global__ __launch_bounds__(256) void gat_edge1_kernel(
    const unsigned short* __restrict__ XL1B, const float* __restrict__ XR1,
    const int* __restrict__ off, const int* __restrict__ csr,
    const float* __restrict__ att, const float* __restrict__ b1,
    const float* __restrict__ g1, const float* __restrict__ be1,
    unsigned short* __restrict__ H1B) {
    int wid = threadIdx.x >> 6;
    int lane = threadIdx.x & 63;
    int node = blockIdx.x * 4 + wid;
    if (node >= NN) return;
    int grp = lane >> 4;
    int sub = lane & 15;
    int cbase = sub << 3;
    const float* xrrow = &XR1[(size_t)node * 128];
    float4 xrA = *(const float4*)&xrrow[cbase];
    float4 xrB = *(const float4*)&xrrow[cbase + 4];
    float4 atA = *(const float4*)&att[cbase];
    float4 atB = *(const float4*)&att[cbase + 4];
    f32x2 xr01 = {xrA.x, xrA.y}, xr23 = {xrA.z, xrA.w};
    f32x2 xr45 = {xrB.x, xrB.y}, xr67 = {xrB.z, xrB.w};
    f32x2 a06_01 = {0.6f * atA.x, 0.6f * atA.y}, a06_23 = {0.6f * atA.z, 0.6f * atA.w};
    f32x2 a06_45 = {0.6f * atB.x, 0.6f * atB.y}, a06_67 = {0.6f * atB.z, 0.6f * atB.w};
    f32x2 a04_01 = {0.4f * atA.x, 0.4f * atA.y}, a04_23 = {0.4f * atA.z, 0.4f * atA.w};
    f32x2 a04_45 = {0.4f * atB.x, 0.4f * atB.y}, a04_67 = {0.4f * atB.z, 0.4f * atB.w};
    f32x2 acc01 = {0.f, 0.f}, acc23 = {0.f, 0.f}, acc45 = {0.f, 0.f}, acc67 = {0.f, 0.f};
    float s = 0.f;
    int jb = off[node], je = off[node + 1];
    int nb = (je - jb + 3) >> 2;
#pragma unroll 2
    for (int k = 0; k < nb; ++k) {
        int eidx = jb + (k << 2) + grp;
        int src = csr[min(eidx, je - 1)];
        uint4 q = *(const uint4*)&XL1B[(size_t)src * 128 + cbase];
        f32x2 xl01 = bf2f2(q.x), xl23 = bf2f2(q.y), xl45 = bf2f2(q.z), xl67 = bf2f2(q.w);
        f32x2 h01 = pk_add(xl01, xr01);
        f32x2 h23 = pk_add(xl23, xr23);
        f32x2 h45 = pk_add(xl45, xr45);
        f32x2 h67 = pk_add(xl67, xr67);
        f32x2 t2 = pk_mul(h01, a06_01);
        t2 = pk_fma(pk_abs2(h01), a04_01, t2);
        t2 = pk_fma(h23, a06_23, t2);
        t2 = pk_fma(pk_abs2(h23), a04_23, t2);
        t2 = pk_fma(h45, a06_45, t2);
        t2 = pk_fma(pk_abs2(h45), a04_45, t2);
        t2 = pk_fma(h67, a06_67, t2);
        t2 = pk_fma(pk_abs2(h67), a04_67, t2);
        float t = t2.x + t2.y;
        t += __shfl_xor(t, 1, 64);
        t += __shfl_xor(t, 2, 64);       // per-head score (4 subs per head)
        t = (eidx < je) ? t : -1e30f;    // exp -> exactly 0 for tail lanes
        float p = __expf(t);
        f32x2 pp;
        pp.x = p;
        pp.y = p;
        acc01 = pk_fma(pp, xl01, acc01);
        acc23 = pk_fma(pp, xl23, acc23);
        acc45 = pk_fma(pp, xl45, acc45);
        acc67 = pk_fma(pp, xl67, acc67);
        s += p;
    }
    // merge the 4 groups' partial sums (plain adds; no max refs)
    float a0 = acc01.x, a1 = acc01.y, a2 = acc23.x, a3 = acc23.y;
    float a4 = acc45.x, a5 = acc45.y, a6 = acc67.x, a7 = acc67.y;
#pragma unroll
    for (int d = 16; d <= 32; d <<= 1) {
        s += __shfl_xor(s, d, 64);
        a0 += __shfl_xor(a0, d, 64);
        a1 += __shfl_xor(a1, d, 64);
        a2 += __shfl_xor(a2, d, 64);
        a3 += __shfl_xor(a3, d, 64);
        a4 += __shfl_xor(a4, d, 64);
        a5 += __shfl_xor(a5, d, 64);
        a6 += __shfl_xor(a6, d, 64);
        a7 += __shfl_xor(a7, d, 64);
    }
    float inv = 1.f / (s + 1e-16f);
    float4 bA = *(const float4*)&b1[cbase];
    float4 bB = *(const float4*)&b1[cbase + 4];
    float o[8];
    o[0] = a0 * inv + bA.x;
    o[1] = a1 * inv + bA.y;
    o[2] = a2 * inv + bA.z;
    o[3] = a3 * inv + bA.w;
    o[4] = a4 * inv + bB.x;
    o[5] = a5 * inv + bB.y;
    o[6] = a6 * inv + bB.z;
    o[7] = a7 * inv + bB.w;
    float sum = 0.f, sq = 0.f;
#pragma unroll
    for (int j = 0; j < 8; ++j) {
        sum += o[j];
        sq = fmaf(o[j], o[j], sq);
    }
#pragma unroll
    for (int d = 1; d <= 8; d <<= 1) {
        sum += __shfl_xor(sum, d, 64);
        sq += __shfl_xor(sq, d, 64);
    }
    float mu = sum * (1.f / 128.f);
    float var = sq * (1.f / 128.f) - mu * mu;
    float rs = rsqrtf(var + 1e-5f);
    if (grp == 0) {
        float4 gA = *(const float4*)&g1[cbase];
        float4 gB = *(const float4*)&g1[cbase + 4];
        float4 eA = *(const float4*)&be1[cbase];
        float4 eB = *(const float4*)&be1[cbase + 4];
        float y[8];
        y[0] = (o[0] - mu) * rs * gA.x + eA.x;
        y[1] = (o[1] - mu) * rs * gA.y + eA.y;
        y[2] = (o[2] - mu) * rs * gA.z + eA.z;
        y[3] = (o[3] - mu) * rs * gA.w + eA.w;
        y[4] = (o[4] - mu) * rs * gB.x + eB.x;
        y[5] = (o[5] - mu) * rs * gB.y + eB.y;
        y[6] = (o[6] - mu) * rs * gB.z + eB.z;
        y[7] = (o[7] - mu) * rs * gB.w + eB.w;
        ushortx8 hw;
#pragma unroll
        for (int j = 0; j < 8; ++j) {
            float yy = y[j] > 0.f ? y[j] : expm1f(y[j]);
            hw[j] = f2bf(yy);
        }
        *(ushortx8*)&H1B[(size_t)node * 128 + cbase] = hw;
    }
}

// ---------------- layer-2 fused edge kernel (4 edges x 16 lanes) -------------
__global__ __launch_bounds__(256) void gat_edge2_kernel(
    const unsigned short* __restrict__ XL2B, const float* __restrict__ XR2,
    const int* __restrict__ off, const int* __restrict__ csr,
    const float* __restrict__ att2, const float* __restrict__ b2,
    float* __restrict__ Y) {
    int wid = threadIdx.x >> 6;
    int lane = threadIdx.x & 63;
    int node = blockIdx.x * 4 + wid;
    if (node >= NN) return;
    int grp = lane >> 4;
    int sub = lane & 15;
    bool chact = sub < 10;
    int cbase = sub << 2;
    int cld = chact ? cbase : 0;  // clamp inactive lanes' load offset in-bounds
    float4 xr = make_float4(0.f, 0.f, 0.f, 0.f);
    float4 at = make_float4(0.f, 0.f, 0.f, 0.f);
    if (chact) {
        xr = *(const float4*)&XR2[(size_t)node * 40 + cbase];
        at = *(const float4*)&att2[cbase];
    }
    f32x2 xr01 = {xr.x, xr.y}, xr23 = {xr.z, xr.w};
    f32x2 a06_01 = {0.6f * at.x, 0.6f * at.y}, a06_23 = {0.6f * at.z, 0.6f * at.w};
    f32x2 a04_01 = {0.4f * at.x, 0.4f * at.y}, a04_23 = {0.4f * at.z, 0.4f * at.w};
    f32x2 acc01 = {0.f, 0.f}, acc23 = {0.f, 0.f};
    float s = 0.f;
    int jb = off[node], je = off[node + 1];
    int nb = (je - jb + 3) >> 2;
#pragma unroll 2
    for (int k = 0; k < nb; ++k) {
        int eidx = jb + (k << 2) + grp;
        int src = csr[min(eidx, je - 1)];
        uint2 q = *(const uint2*)&XL2B[(size_t)src * 40 + cld];
        f32x2 xl01 = bf2f2(q.x), xl23 = bf2f2(q.y);
        f32x2 h01 = pk_add(xl01, xr01);
        f32x2 h23 = pk_add(xl23, xr23);
        f32x2 t2 = pk_mul(h01, a06_01);
        t2 = pk_fma(pk_abs2(h01), a04_01, t2);
        t2 = pk_fma(h23, a06_23, t2);
        t2 = pk_fma(pk_abs2(h23), a04_23, t2);
        float t = t2.x + t2.y;
        t += __shfl_xor(t, 1, 64);
        t += __shfl_xor(t, 2, 64);
        t += __shfl_xor(t, 4, 64);
        t += __shfl_xor(t, 8, 64);       // single head: reduce all 16 subs
        t = (eidx < je) ? t : -1e30f;
        float p = __expf(t);
        f32x2 pp;
        pp.x = p;
        pp.y = p;
        acc01 = pk_fma(pp, xl01, acc01);
        acc23 = pk_fma(pp, xl23, acc23);
        s += p;
    }
    float a0 = acc01.x, a1 = acc01.y, a2 = acc23.x, a3 = acc23.y;
#pragma unroll
    for (int d = 16; d <= 32; d <<= 1) {
        s += __shfl_xor(s, d, 64);
        a0 += __shfl_xor(a0, d, 64);
        a1 += __shfl_xor(a1, d, 64);
        a2 += __shfl_xor(a2, d, 64);
        a3 += __shfl_xor(a3, d, 64);
    }
    if (grp == 0 && chact) {
        float inv = 1.f / (s + 1e-16f);
        float4 bb = *(const float4*)&b2[cbase];
        float4 y;
        y.x = a0 * inv + bb.x;
        y.y = a1 * inv + bb.y;
        y.z = a2 * inv + bb.z;
        y.w = a3 * inv + bb.w;
        *(float4*)&Y[(size_t)node * 40 + cbase] = y;
    }
}

// ---------------- launch ----------------
extern "C" void kernel_launch(void* const* d_in, const int* in_sizes, int n_in,
                              void* d_out, int out_size, void* d_ws, size_t ws_size,
                              hipStream_t stream) {
    const float* x = (const float*)d_in[0];
    const int* ei = (const int*)d_in[1];
    const float* Wl1 = (const float*)d_in[2];
    const float* bl1 = (const float*)d_in[3];
    const float* Wr1 = (const float*)d_in[4];
    const float* br1 = (const float*)d_in[5];
    const float* att1 = (const float*)d_in[6];
    const float* b1 = (const float*)d_in[7];
    const float* g1 = (const float*)d_in[8];
    const float* be1 = (const float*)d_in[9];
    const float* Wl2 = (const float*)d_in[10];
    const float* bl2 = (const float*)d_in[11];
    const float* Wr2 = (const float*)d_in[12];
    const float* br2 = (const float*)d_in[13];
    const float* att2 = (const float*)d_in[14];
    const float* b2 = (const float*)d_in[15];

    const int* srcs = ei;
    const int* tgts = ei + EE;

    char* ws = (char*)d_ws;
    unsigned short* XBF = (unsigned short*)(ws + OFF_XBF);
    unsigned short* XL1B = (unsigned short*)(ws + OFF_XL1B);
    float* XR1 = (float*)(ws + OFF_XR1);
    unsigned short* H1B = (unsigned short*)(ws + OFF_H1B);
    unsigned short* XL2B = (unsigned short*)(ws + OFF_XL2B);
    float* XR2 = (float*)(ws + OFF_XR2);
    unsigned short* BP1 = (unsigned short*)(ws + OFF_BP1);
    unsigned short* BP2 = (unsigned short*)(ws + OFF_BP2);
    float* BB1 = (float*)(ws + OFF_BB1);
    float* BB2 = (float*)(ws + OFF_BB2);
    int* DEG = (int*)(ws + OFF_DEG);
    int* OFFS = (int*)(ws + OFF_OFFS);
    int* CUR = (int*)(ws + OFF_CUR);
    int* CSR = (int*)(ws + OFF_CSR);
    int* BSUM = (int*)(ws + OFF_BSUM);

    float* Y = (float*)d_out;

    // prep: zero DEG + pack weights + x->bf16
    prep_kernel<<<(NN * 128 / 8 + 255) / 256, 256, 0, stream>>>(
        x, XBF, Wl1, bl1, Wr1, br1, Wl2, bl2, Wr2, br2, BP1, BB1, BP2, BB2, DEG);

    // CSR build (parallel scan)
    hist_kernel<<<(EE + 255) / 256, 256, 0, stream>>>(tgts, DEG, EE);
    scan_bsum_kernel<<<NB_SCAN, 1024, 0, stream>>>(DEG, BSUM, NN);
    scan_boff_kernel<<<1, 64, 0, stream>>>(BSUM, NB_SCAN);
    scan_final_kernel<<<NB_SCAN, 1024, 0, stream>>>(DEG, BSUM, OFFS, CUR, NN);
    scatter_kernel<<<(EE + 255) / 256, 256, 0, stream>>>(srcs, tgts, CUR, CSR, EE);

    // layer-1 GEMM (MFMA): xl -> bf16 XL1B, xr -> f32 XR1
    gemm_mfma_kernel<<<(3125 + 3) / 4, 256, 0, stream>>>(XBF, BP1, BB1, XL1B, XR1, NN, 16, 128);

    // layer-1 fused edge pass (+bias+LN+ELU) -> H1 (bf16)
    gat_edge1_kernel<<<(NN + 3) / 4, 256, 0, stream>>>(XL1B, XR1, OFFS, CSR, att1, b1, g1, be1, H1B);

    // layer-2 GEMM (MFMA): xl -> bf16 XL2B, xr -> f32 XR2
    gemm_mfma_kernel<<<(3125 + 3) / 4, 256, 0, stream>>>(H1B, BP2, BB2, XL2B, XR2, NN, 5, 40);

    // layer-2 fused edge pass -> output
    gat_edge2_kernel<<<(NN + 3) / 4, 256, 0, stream>>>(XL2B, XR2, OFFS, CSR, att2, b2, Y);
}

// Round 7
// 202.147 us; speedup vs baseline: 1.1197x; 1.1197x over previous
//
#include <hip/hip_runtime.h>
#include <hip/hip_bf16.h>
#include <math.h>

// Problem constants
#define NN 50000
#define EE 800000
#define NB_SCAN 49  // ceil(50000/1024)

typedef __attribute__((ext_vector_type(8))) short bf16x8;
typedef __attribute__((ext_vector_type(4))) float f32x4;
typedef __attribute__((ext_vector_type(2))) float f32x2;
typedef __attribute__((ext_vector_type(8))) unsigned short ushortx8;

// ---------------- workspace layout (bytes), all 256B-aligned ----------------
#define OFF_XBF  ((size_t)0)                        // N*128 bf16 (x converted)
#define SZ_XBF   ((size_t)NN * 128 * 2)
#define OFF_XL1B (OFF_XBF + SZ_XBF)                 // N*128 bf16 (xl layer1)
#define SZ_XL1B  ((size_t)NN * 128 * 2)
#define OFF_XR1  (OFF_XL1B + SZ_XL1B)               // N*128 f32 (xr layer1)
#define SZ_XR1   ((size_t)NN * 128 * 4)
#define OFF_H1B  (OFF_XR1 + SZ_XR1)                 // N*128 bf16
#define SZ_H1B   ((size_t)NN * 128 * 2)
#define OFF_XL2B (OFF_H1B + SZ_H1B)                 // N*40 bf16
#define SZ_XL2B  ((size_t)NN * 40 * 2)
#define OFF_XR2  (OFF_XL2B + SZ_XL2B)               // N*40 f32
#define SZ_XR2   ((size_t)NN * 40 * 4)
#define OFF_BP1  (OFF_XR2 + SZ_XR2)                 // 4*16*64*8 bf16
#define SZ_BP1   ((size_t)32768 * 2)
#define OFF_BP2  (OFF_BP1 + SZ_BP1)                 // 4*5*64*8 bf16
#define SZ_BP2   ((size_t)10240 * 2)
#define OFF_BB1  (OFF_BP2 + SZ_BP2)                 // 256 f32
#define SZ_BB1   ((size_t)1024)
#define OFF_BB2  (OFF_BB1 + SZ_BB1)                 // 80 f32 (pad)
#define SZ_BB2   ((size_t)512)
#define OFF_DEG  (OFF_BB2 + SZ_BB2)                 // N int
#define SZ_DEG   ((size_t)NN * 4)
#define OFF_OFFS (OFF_DEG + SZ_DEG)                 // (N+1) int (pad)
#define SZ_OFFS  ((size_t)200192)
#define OFF_CUR  (OFF_OFFS + SZ_OFFS)               // N int
#define SZ_CUR   ((size_t)NN * 4)
#define OFF_CSR  (OFF_CUR + SZ_CUR)                 // E int
#define SZ_CSR   ((size_t)EE * 4)
#define OFF_BSUM (OFF_CSR + SZ_CSR)                 // 64 int
#define SZ_BSUM  ((size_t)256)

__device__ __forceinline__ unsigned short f2bf(float f) {
    union { float f; unsigned u; } v;
    v.f = f;
    unsigned r = v.u + 0x7fffu + ((v.u >> 16) & 1u);
    return (unsigned short)(r >> 16);
}
__device__ __forceinline__ f32x2 bf2f2(unsigned u) {
    union { unsigned u; float f; } lo, hi;
    lo.u = u << 16;
    hi.u = u & 0xffff0000u;
    f32x2 r;
    r.x = lo.f;
    r.y = hi.f;
    return r;
}

// packed f32 VOP3P helpers
__device__ __forceinline__ f32x2 pk_add(f32x2 a, f32x2 b) {
    f32x2 d;
    asm("v_pk_add_f32 %0, %1, %2" : "=v"(d) : "v"(a), "v"(b));
    return d;
}
__device__ __forceinline__ f32x2 pk_mul(f32x2 a, f32x2 b) {
    f32x2 d;
    asm("v_pk_mul_f32 %0, %1, %2" : "=v"(d) : "v"(a), "v"(b));
    return d;
}
__device__ __forceinline__ f32x2 pk_fma(f32x2 a, f32x2 b, f32x2 c) {
    f32x2 d;
    asm("v_pk_fma_f32 %0, %1, %2, %3" : "=v"(d) : "v"(a), "v"(b), "v"(c));
    return d;
}
__device__ __forceinline__ f32x2 pk_abs2(f32x2 a) {
    f32x2 r;
    r.x = __builtin_fabsf(a.x);
    r.y = __builtin_fabsf(a.y);
    return r;
}

// DPP cross-lane adds (row=16 lanes). ctrl: quad_perm xor1=0xB1, xor2=0x4E,
// row_ror:4=0x124, row_ror:8=0x128. All lanes active at call sites.
#define DPP_ADD(t, ctrl) \
    ((t) + __int_as_float(__builtin_amdgcn_mov_dpp(__float_as_int(t), (ctrl), 0xF, 0xF, true)))

// ---------------- fused prep: zero DEG + pack weights + cvt x -> bf16 --------
__global__ void prep_kernel(
    const float* __restrict__ x, unsigned short* __restrict__ XBF,
    const float* __restrict__ Wl1, const float* __restrict__ bl1,
    const float* __restrict__ Wr1, const float* __restrict__ br1,
    const float* __restrict__ Wl2, const float* __restrict__ bl2,
    const float* __restrict__ Wr2, const float* __restrict__ br2,
    unsigned short* __restrict__ BP1, float* __restrict__ BB1,
    unsigned short* __restrict__ BP2, float* __restrict__ BB2,
    int* __restrict__ DEG) {
    int i = blockIdx.x * blockDim.x + threadIdx.x;
    if (i < NN * 128 / 8) {
        const float4* p = (const float4*)x + (size_t)i * 2;
        float4 v0 = p[0], v1 = p[1];
        ushortx8 o;
        o[0] = f2bf(v0.x); o[1] = f2bf(v0.y); o[2] = f2bf(v0.z); o[3] = f2bf(v0.w);
        o[4] = f2bf(v1.x); o[5] = f2bf(v1.y); o[6] = f2bf(v1.z); o[7] = f2bf(v1.w);
        *((ushortx8*)XBF + i) = o;
    }
    if (i < NN) DEG[i] = 0;
    if (i < 32768) {  // layer 1 B-pack: NT=16
        int j = i & 7, l = (i >> 3) & 63, nt = (i >> 9) & 15, kt = i >> 13;
        int k = kt * 32 + ((l >> 4) << 3) + j;
        int n = nt * 16 + (l & 15);
        float v = (n < 128) ? Wl1[k * 128 + n] : Wr1[k * 128 + (n - 128)];
        BP1[i] = f2bf(v);
    }
    if (i < 10240) {  // layer 2 B-pack: NT=5
        int j = i & 7, l = (i >> 3) & 63;
        int rest = i >> 9;
        int nt = rest % 5, kt = rest / 5;
        int k = kt * 32 + ((l >> 4) << 3) + j;
        int n = nt * 16 + (l & 15);
        float v = (n < 40) ? Wl2[k * 40 + n] : Wr2[k * 40 + (n - 40)];
        BP2[i] = f2bf(v);
    }
    if (i < 256) BB1[i] = (i < 128) ? bl1[i] : br1[i - 128];
    if (i < 80) BB2[i] = (i < 40) ? bl2[i] : br2[i - 40];
}

__global__ void hist_kernel(const int* __restrict__ tgts, int* __restrict__ deg, int e_) {
    int e = blockIdx.x * blockDim.x + threadIdx.x;
    if (e < e_) atomicAdd(&deg[tgts[e]], 1);
}

// ---------------- parallel scan (2 kernels) ----------------
__global__ __launch_bounds__(1024) void scan_bsum_kernel(
    const int* __restrict__ deg, int* __restrict__ bsum, int n) {
    __shared__ int ws[16];
    int lane = threadIdx.x & 63, w = threadIdx.x >> 6;
    int i = blockIdx.x * 1024 + threadIdx.x;
    int v = (i < n) ? deg[i] : 0;
#pragma unroll
    for (int d = 32; d >= 1; d >>= 1) v += __shfl_xor(v, d, 64);
    if (lane == 0) ws[w] = v;
    __syncthreads();
    if (threadIdx.x < 16) {
        int xv = ws[threadIdx.x];
#pragma unroll
        for (int d = 8; d >= 1; d >>= 1) xv += __shfl_xor(xv, d, 16);
        if (threadIdx.x == 0) bsum[blockIdx.x] = xv;
    }
}

__global__ __launch_bounds__(1024) void scan_final_kernel(
    const int* __restrict__ deg, const int* __restrict__ bsum,
    int* __restrict__ off, int* __restrict__ cur, int n) {
    __shared__ int wsum[16];
    __shared__ int carrySh;
    int lane = threadIdx.x & 63, w = threadIdx.x >> 6;
    // wave 0: carry = sum of bsum[0..blockIdx.x)
    if (threadIdx.x < 64) {
        int v = ((int)threadIdx.x < (int)blockIdx.x) ? bsum[threadIdx.x] : 0;
#pragma unroll
        for (int d = 32; d >= 1; d >>= 1) v += __shfl_xor(v, d, 64);
        if (threadIdx.x == 0) carrySh = v;
    }
    int i = blockIdx.x * 1024 + threadIdx.x;
    int v = (i < n) ? deg[i] : 0;
    int incl = v;
#pragma unroll
    for (int d = 1; d < 64; d <<= 1) {
        int t = __shfl_up(incl, d, 64);
        if (lane >= d) incl += t;
    }
    if (lane == 63) wsum[w] = incl;
    __syncthreads();
    if (threadIdx.x < 16) {
        int xv = wsum[threadIdx.x];
#pragma unroll
        for (int d = 1; d < 16; d <<= 1) {
            int t = __shfl_up(xv, d, 16);
            if ((int)threadIdx.x >= d) xv += t;
        }
        wsum[threadIdx.x] = xv;
    }
    __syncthreads();
    int add = (w > 0) ? wsum[w - 1] : 0;
    int carry = carrySh;
    if (i < n) {
        int tot = carry + incl + add;
        off[i + 1] = tot;
        cur[i] = tot - v;
    }
    if (i == 0) off[0] = 0;
}

__global__ void scatter_kernel(const int* __restrict__ srcs, const int* __restrict__ tgts,
                               int* __restrict__ cur, int* __restrict__ csr, int e_) {
    int e = blockIdx.x * blockDim.x + threadIdx.x;
    if (e < e_) {
        int t = tgts[e];
        int pos = atomicAdd(&cur[t], 1);
        csr[pos] = srcs[e];
    }
}

// ---------------- bf16 MFMA GEMM with split bf16/f32 output ------------------
__global__ __launch_bounds__(256) void gemm_mfma_kernel(
    const unsigned short* __restrict__ Abf, const unsigned short* __restrict__ BP,
    const float* __restrict__ bias, unsigned short* __restrict__ Cbf,
    float* __restrict__ Cf, int M, int NT, int NSPLIT) {
    int wave = (blockIdx.x * blockDim.x + threadIdx.x) >> 6;
    int lane = threadIdx.x & 63;
    int r0 = wave * 16;
    if (r0 >= M) return;
    int koff = (lane >> 4) << 3;
    const unsigned short* ap = &Abf[(size_t)(r0 + (lane & 15)) * 128 + koff];
    bf16x8 a0 = *(const bf16x8*)(ap);
    bf16x8 a1 = *(const bf16x8*)(ap + 32);
    bf16x8 a2 = *(const bf16x8*)(ap + 64);
    bf16x8 a3 = *(const bf16x8*)(ap + 96);
    int NR = (NT << 4) - NSPLIT;
    int col = lane & 15;
    int rb = r0 + ((lane >> 4) << 2);
    size_t ktStride = (size_t)NT * 512;
    for (int nt = 0; nt < NT; ++nt) {
        const unsigned short* bp = &BP[((size_t)nt * 64 + lane) * 8];
        f32x4 acc = {0.f, 0.f, 0.f, 0.f};
        acc = __builtin_amdgcn_mfma_f32_16x16x32_bf16(a0, *(const bf16x8*)(bp), acc, 0, 0, 0);
        acc = __builtin_amdgcn_mfma_f32_16x16x32_bf16(a1, *(const bf16x8*)(bp + ktStride), acc, 0, 0, 0);
        acc = __builtin_amdgcn_mfma_f32_16x16x32_bf16(a2, *(const bf16x8*)(bp + 2 * ktStride), acc, 0, 0, 0);
        acc = __builtin_amdgcn_mfma_f32_16x16x32_bf16(a3, *(const bf16x8*)(bp + 3 * ktStride), acc, 0, 0, 0);
        int c = (nt << 4) + col;
        float bb = bias[c];
        if (c < NSPLIT) {
#pragma unroll
            for (int j = 0; j < 4; ++j) Cbf[(size_t)(rb + j) * NSPLIT + c] = f2bf(acc[j] + bb);
        } else {
#pragma unroll
            for (int j = 0; j < 4; ++j) Cf[(size_t)(rb + j) * NR + (c - NSPLIT)] = acc[j] + bb;
        }
    }
}

// ---------------- layer-1 fused edge kernel --------------------------------
// 4 edges x 16 lanes per wave; 16-edge chunks: one coalesced csr load fetches
// all 16 src indices, 4 shuffles distribute them, and all 4 gathers issue
// back-to-back (MLP=4). Score reduce over 4 subs via DPP quad_perm.
__global__ __launch_bounds__(256) void gat_edge1_kernel(
    const unsigned short* __restrict__ XL1B, const float* __restrict__ XR1,
    const int* __restrict__ off, const int* __restrict__ csr,
    const float* __restrict__ att, const float* __restrict__ b1,
    const float* __restrict__ g1, const float* __restrict__ be1,
    unsigned short* __restrict__ H1B) {
    int wid = threadIdx.x >> 6;
    int lane = threadIdx.x & 63;
    int node = blockIdx.x * 4 + wid;
    if (node >= NN) return;
    int grp = lane >> 4;
    int sub = lane & 15;
    int cbase = sub << 3;
    const float* xrrow = &XR1[(size_t)node * 128];
    float4 xrA = *(const float4*)&xrrow[cbase];
    float4 xrB = *(const float4*)&xrrow[cbase + 4];
    float4 atA = *(const float4*)&att[cbase];
    float4 atB = *(const float4*)&att[cbase + 4];
    f32x2 xr01 = {xrA.x, xrA.y}, xr23 = {xrA.z, xrA.w};
    f32x2 xr45 = {xrB.x, xrB.y}, xr67 = {xrB.z, xrB.w};
    f32x2 at01 = {atA.x, atA.y}, at23 = {atA.z, atA.w};
    f32x2 at45 = {atB.x, atB.y}, at67 = {atB.z, atB.w};
    f32x2 c06 = {0.6f, 0.6f}, c04 = {0.4f, 0.4f};
    f32x2 acc01 = {0.f, 0.f}, acc23 = {0.f, 0.f}, acc45 = {0.f, 0.f}, acc67 = {0.f, 0.f};
    float s = 0.f;
    int jb = off[node], je = off[node + 1];
    int deg = je - jb;

    auto process = [&](uint4 q, int eo) {
        f32x2 xl01 = bf2f2(q.x), xl23 = bf2f2(q.y), xl45 = bf2f2(q.z), xl67 = bf2f2(q.w);
        f32x2 h01 = pk_add(xl01, xr01);
        f32x2 h23 = pk_add(xl23, xr23);
        f32x2 h45 = pk_add(xl45, xr45);
        f32x2 h67 = pk_add(xl67, xr67);
        f32x2 u01 = pk_fma(pk_abs2(h01), c04, pk_mul(h01, c06));
        f32x2 u23 = pk_fma(pk_abs2(h23), c04, pk_mul(h23, c06));
        f32x2 u45 = pk_fma(pk_abs2(h45), c04, pk_mul(h45, c06));
        f32x2 u67 = pk_fma(pk_abs2(h67), c04, pk_mul(h67, c06));
        f32x2 t2 = pk_mul(u01, at01);
        t2 = pk_fma(u23, at23, t2);
        t2 = pk_fma(u45, at45, t2);
        t2 = pk_fma(u67, at67, t2);
        float t = t2.x + t2.y;
        t = DPP_ADD(t, 0xB1);   // xor 1 (quad_perm)
        t = DPP_ADD(t, 0x4E);   // xor 2 (quad_perm) -> per-head score
        t = (eo < deg) ? t : -1e30f;
        float p = __expf(t);
        f32x2 pp;
        pp.x = p;
        pp.y = p;
        acc01 = pk_fma(pp, xl01, acc01);
        acc23 = pk_fma(pp, xl23, acc23);
        acc45 = pk_fma(pp, xl45, acc45);
        acc67 = pk_fma(pp, xl67, acc67);
        s += p;
    };

    for (int ch = 0; ch < deg; ch += 16) {
        int sidx = csr[min(jb + ch + sub, je - 1)];
        int s0 = __shfl(sidx, grp, 16);
        int s1 = __shfl(sidx, 4 + grp, 16);
        int s2 = __shfl(sidx, 8 + grp, 16);
        int s3 = __shfl(sidx, 12 + grp, 16);
        uint4 q0 = *(const uint4*)&XL1B[(size_t)s0 * 128 + cbase];
        uint4 q1 = *(const uint4*)&XL1B[(size_t)s1 * 128 + cbase];
        uint4 q2 = *(const uint4*)&XL1B[(size_t)s2 * 128 + cbase];
        uint4 q3 = *(const uint4*)&XL1B[(size_t)s3 * 128 + cbase];
        process(q0, ch + grp);
        process(q1, ch + 4 + grp);
        process(q2, ch + 8 + grp);
        process(q3, ch + 12 + grp);
    }

    // merge the 4 groups' partial sums
    float a0 = acc01.x, a1 = acc01.y, a2 = acc23.x, a3 = acc23.y;
    float a4 = acc45.x, a5 = acc45.y, a6 = acc67.x, a7 = acc67.y;
#pragma unroll
    for (int d = 16; d <= 32; d <<= 1) {
        s += __shfl_xor(s, d, 64);
        a0 += __shfl_xor(a0, d, 64);
        a1 += __shfl_xor(a1, d, 64);
        a2 += __shfl_xor(a2, d, 64);
        a3 += __shfl_xor(a3, d, 64);
        a4 += __shfl_xor(a4, d, 64);
        a5 += __shfl_xor(a5, d, 64);
        a6 += __shfl_xor(a6, d, 64);
        a7 += __shfl_xor(a7, d, 64);
    }
    float inv = 1.f / (s + 1e-16f);
    float4 bA = *(const float4*)&b1[cbase];
    float4 bB = *(const float4*)&b1[cbase + 4];
    float o[8];
    o[0] = a0 * inv + bA.x;
    o[1] = a1 * inv + bA.y;
    o[2] = a2 * inv + bA.z;
    o[3] = a3 * inv + bA.w;
    o[4] = a4 * inv + bB.x;
    o[5] = a5 * inv + bB.y;
    o[6] = a6 * inv + bB.z;
    o[7] = a7 * inv + bB.w;
    float sum = 0.f, sq = 0.f;
#pragma unroll
    for (int j = 0; j < 8; ++j) {
        sum += o[j];
        sq = fmaf(o[j], o[j], sq);
    }
#pragma unroll
    for (int d = 1; d <= 8; d <<= 1) {
        sum += __shfl_xor(sum, d, 64);
        sq += __shfl_xor(sq, d, 64);
    }
    float mu = sum * (1.f / 128.f);
    float var = sq * (1.f / 128.f) - mu * mu;
    float rs = rsqrtf(var + 1e-5f);
    if (grp == 0) {
        float4 gA = *(const float4*)&g1[cbase];
        float4 gB = *(const float4*)&g1[cbase + 4];
        float4 eA = *(const float4*)&be1[cbase];
        float4 eB = *(const float4*)&be1[cbase + 4];
        float y[8];
        y[0] = (o[0] - mu) * rs * gA.x + eA.x;
        y[1] = (o[1] - mu) * rs * gA.y + eA.y;
        y[2] = (o[2] - mu) * rs * gA.z + eA.z;
        y[3] = (o[3] - mu) * rs * gA.w + eA.w;
        y[4] = (o[4] - mu) * rs * gB.x + eB.x;
        y[5] = (o[5] - mu) * rs * gB.y + eB.y;
        y[6] = (o[6] - mu) * rs * gB.z + eB.z;
        y[7] = (o[7] - mu) * rs * gB.w + eB.w;
        ushortx8 hw;
#pragma unroll
        for (int j = 0; j < 8; ++j) {
            float yy = y[j] > 0.f ? y[j] : expm1f(y[j]);
            hw[j] = f2bf(yy);
        }
        *(ushortx8*)&H1B[(size_t)node * 128 + cbase] = hw;
    }
}

// ---------------- layer-2 fused edge kernel --------------------------------
// Same chunked structure. Single head: 16-sub reduce via DPP quad_perm + ror.
__global__ __launch_bounds__(256) void gat_edge2_kernel(
    const unsigned short* __restrict__ XL2B, const float* __restrict__ XR2,
    const int* __restrict__ off, const int* __restrict__ csr,
    const float* __restrict__ att2, const float* __restrict__ b2,
    float* __restrict__ Y) {
    int wid = threadIdx.x >> 6;
    int lane = threadIdx.x & 63;
    int node = blockIdx.x * 4 + wid;
    if (node >= NN) return;
    int grp = lane >> 4;
    int sub = lane & 15;
    bool chact = sub < 10;
    int cbase = sub << 2;
    int cld = chact ? cbase : 0;
    float4 xr = make_float4(0.f, 0.f, 0.f, 0.f);
    float4 at = make_float4(0.f, 0.f, 0.f, 0.f);
    if (chact) {
        xr = *(const float4*)&XR2[(size_t)node * 40 + cbase];
        at = *(const float4*)&att2[cbase];
    }
    f32x2 xr01 = {xr.x, xr.y}, xr23 = {xr.z, xr.w};
    f32x2 at01 = {at.x, at.y}, at23 = {at.z, at.w};
    f32x2 c06 = {0.6f, 0.6f}, c04 = {0.4f, 0.4f};
    f32x2 acc01 = {0.f, 0.f}, acc23 = {0.f, 0.f};
    float s = 0.f;
    int jb = off[node], je = off[node + 1];
    int deg = je - jb;

    auto process = [&](uint2 q, int eo) {
        f32x2 xl01 = bf2f2(q.x), xl23 = bf2f2(q.y);
        f32x2 h01 = pk_add(xl01, xr01);
        f32x2 h23 = pk_add(xl23, xr23);
        f32x2 u01 = pk_fma(pk_abs2(h01), c04, pk_mul(h01, c06));
        f32x2 u23 = pk_fma(pk_abs2(h23), c04, pk_mul(h23, c06));
        f32x2 t2 = pk_mul(u01, at01);
        t2 = pk_fma(u23, at23, t2);
        float t = t2.x + t2.y;
        t = DPP_ADD(t, 0xB1);    // xor 1
        t = DPP_ADD(t, 0x4E);    // xor 2
        t = DPP_ADD(t, 0x124);   // row_ror:4  (quad rotation)
        t = DPP_ADD(t, 0x128);   // row_ror:8  -> full 16-sub sum, all lanes
        t = (eo < deg) ? t : -1e30f;
        float p = __expf(t);
        f32x2 pp;
        pp.x = p;
        pp.y = p;
        acc01 = pk_fma(pp, xl01, acc01);
        acc23 = pk_fma(pp, xl23, acc23);
        s += p;
    };

    for (int ch = 0; ch < deg; ch += 16) {
        int sidx = csr[min(jb + ch + sub, je - 1)];
        int s0 = __shfl(sidx, grp, 16);
        int s1 = __shfl(sidx, 4 + grp, 16);
        int s2 = __shfl(sidx, 8 + grp, 16);
        int s3 = __shfl(sidx, 12 + grp, 16);
        uint2 q0 = *(const uint2*)&XL2B[(size_t)s0 * 40 + cld];
        uint2 q1 = *(const uint2*)&XL2B[(size_t)s1 * 40 + cld];
        uint2 q2 = *(const uint2*)&XL2B[(size_t)s2 * 40 + cld];
        uint2 q3 = *(const uint2*)&XL2B[(size_t)s3 * 40 + cld];
        process(q0, ch + grp);
        process(q1, ch + 4 + grp);
        process(q2, ch + 8 + grp);
        process(q3, ch + 12 + grp);
    }

    float a0 = acc01.x, a1 = acc01.y, a2 = acc23.x, a3 = acc23.y;
#pragma unroll
    for (int d = 16; d <= 32; d <<= 1) {
        s += __shfl_xor(s, d, 64);
        a0 += __shfl_xor(a0, d, 64);
        a1 += __shfl_xor(a1, d, 64);
        a2 += __shfl_xor(a2, d, 64);
        a3 += __shfl_xor(a3, d, 64);
    }
    if (grp == 0 && chact) {
        float inv = 1.f / (s + 1e-16f);
        float4 bb = *(const float4*)&b2[cbase];
        float4 y;
        y.x = a0 * inv + bb.x;
        y.y = a1 * inv + bb.y;
        y.z = a2 * inv + bb.z;
        y.w = a3 * inv + bb.w;
        *(float4*)&Y[(size_t)node * 40 + cbase] = y;
    }
}

// ---------------- launch ----------------
extern "C" void kernel_launch(void* const* d_in, const int* in_sizes, int n_in,
                              void* d_out, int out_size, void* d_ws, size_t ws_size,
                              hipStream_t stream) {
    const float* x = (const float*)d_in[0];
    const int* ei = (const int*)d_in[1];
    const float* Wl1 = (const float*)d_in[2];
    const float* bl1 = (const float*)d_in[3];
    const float* Wr1 = (const float*)d_in[4];
    const float* br1 = (const float*)d_in[5];
    const float* att1 = (const float*)d_in[6];
    const float* b1 = (const float*)d_in[7];
    const float* g1 = (const float*)d_in[8];
    const float* be1 = (const float*)d_in[9];
    const float* Wl2 = (const float*)d_in[10];
    const float* bl2 = (const float*)d_in[11];
    const float* Wr2 = (const float*)d_in[12];
    const float* br2 = (const float*)d_in[13];
    const float* att2 = (const float*)d_in[14];
    const float* b2 = (const float*)d_in[15];

    const int* srcs = ei;
    const int* tgts = ei + EE;

    char* ws = (char*)d_ws;
    unsigned short* XBF = (unsigned short*)(ws + OFF_XBF);
    unsigned short* XL1B = (unsigned short*)(ws + OFF_XL1B);
    float* XR1 = (float*)(ws + OFF_XR1);
    unsigned short* H1B = (unsigned short*)(ws + OFF_H1B);
    unsigned short* XL2B = (unsigned short*)(ws + OFF_XL2B);
    float* XR2 = (float*)(ws + OFF_XR2);
    unsigned short* BP1 = (unsigned short*)(ws + OFF_BP1);
    unsigned short* BP2 = (unsigned short*)(ws + OFF_BP2);
    float* BB1 = (float*)(ws + OFF_BB1);
    float* BB2 = (float*)(ws + OFF_BB2);
    int* DEG = (int*)(ws + OFF_DEG);
    int* OFFS = (int*)(ws + OFF_OFFS);
    int* CUR = (int*)(ws + OFF_CUR);
    int* CSR = (int*)(ws + OFF_CSR);
    int* BSUM = (int*)(ws + OFF_BSUM);

    float* Y = (float*)d_out;

    // prep: zero DEG + pack weights + x->bf16
    prep_kernel<<<(NN * 128 / 8 + 255) / 256, 256, 0, stream>>>(
        x, XBF, Wl1, bl1, Wr1, br1, Wl2, bl2, Wr2, br2, BP1, BB1, BP2, BB2, DEG);

    // CSR build (parallel scan, carry folded into final)
    hist_kernel<<<(EE + 255) / 256, 256, 0, stream>>>(tgts, DEG, EE);
    scan_bsum_kernel<<<NB_SCAN, 1024, 0, stream>>>(DEG, BSUM, NN);
    scan_final_kernel<<<NB_SCAN, 1024, 0, stream>>>(DEG, BSUM, OFFS, CUR, NN);
    scatter_kernel<<<(EE + 255) / 256, 256, 0, stream>>>(srcs, tgts, CUR, CSR, EE);

    // layer-1 GEMM (MFMA): xl -> bf16 XL1B, xr -> f32 XR1
    gemm_mfma_kernel<<<(3125 + 3) / 4, 256, 0, stream>>>(XBF, BP1, BB1, XL1B, XR1, NN, 16, 128);

    // layer-1 fused edge pass (+bias+LN+ELU) -> H1 (bf16)
    gat_edge1_kernel<<<(NN + 3) / 4, 256, 0, stream>>>(XL1B, XR1, OFFS, CSR, att1, b1, g1, be1, H1B);

    // layer-2 GEMM (MFMA): xl -> bf16 XL2B, xr -> f32 XR2
    gemm_mfma_kernel<<<(3125 + 3) / 4, 256, 0, stream>>>(H1B, BP2, BB2, XL2B, XR2, NN, 5, 40);

    // layer-2 fused edge pass -> output
    gat_edge2_kernel<<<(NN + 3) / 4, 256, 0, stream>>>(XL2B, XR2, OFFS, CSR, att2, b2, Y);
}